// Round 4
// baseline (334.657 us; speedup 1.0000x reference)
//
#include <hip/hip_runtime.h>
#include <hip/hip_bf16.h>
#include <math.h>

// Problem constants
#define BB 8
#define NN 1024
#define SS 64
#define VCC 8
#define EE 64
#define HH 4
#define HDD 16

// d_out layout: s (B*N*S=524288) | v (B*N*VC*3=196608) | pd (B*N*N=8388608)
#define OUT_S_OFF 0
#define OUT_V_OFF 524288
#define OUT_PD_OFF 720896

// 3-adic valuation capped at 10, zero for d==0
__device__ __forceinline__ int val3(int d) {
    int c = 0;
    unsigned ud = (unsigned)d;
    c += (ud % 3u == 0u);
    c += (ud % 9u == 0u);
    c += (ud % 27u == 0u);
    c += (ud % 81u == 0u);
    c += (ud % 243u == 0u);
    c += (ud % 729u == 0u);
    c += (ud % 2187u == 0u);
    c += (ud % 6561u == 0u);
    c += (ud % 19683u == 0u);
    c += (ud % 59049u == 0u);
    return d > 0 ? c : 0;
}

__device__ __forceinline__ float silu_f(float x) {
    return x / (1.0f + expf(-x));
}
__device__ __forceinline__ float sigmoid_f(float x) {
    return 1.0f / (1.0f + expf(-x));
}

// ---------------- Kernel A: pd matrix + row means ----------------
// Block = 16 i-rows x 1024 j. coords staged once in LDS (SoA); per-thread
// j-coords in registers reused across the 16 rows. Grid = B * 64 = 512.
#define IR 16
__global__ __launch_bounds__(256) void pd_kernel(const float* __restrict__ coords,
                                                 float* __restrict__ pd_out,
                                                 float* __restrict__ pdmean) {
    const int bi = blockIdx.x;            // b*64 + itile
    const int b = bi >> 6;
    const int ibase = (bi & 63) * IR;
    const int tid = threadIdx.x;
    const float* cb = coords + (size_t)b * NN * 3;

    __shared__ float sx[1024];
    __shared__ float sy[1024];
    __shared__ float sz[1024];
    __shared__ float red[IR][4];

    for (int idx = tid; idx < 3072; idx += 256) {
        float v = cb[idx];
        int j = idx / 3;
        int c = idx - j * 3;
        float* dst = (c == 0) ? sx : (c == 1) ? sy : sz;
        dst[j] = v;
    }
    __syncthreads();

    const int j0 = tid * 4;
    float4 x4 = *(const float4*)&sx[j0];
    float4 y4 = *(const float4*)&sy[j0];
    float4 z4 = *(const float4*)&sz[j0];
    float xs[4] = {x4.x, x4.y, x4.z, x4.w};
    float ys[4] = {y4.x, y4.y, y4.z, y4.w};
    float zs[4] = {z4.x, z4.y, z4.z, z4.w};

    const float kLog2_3_over3 = 0.5283208335737187f;  // log2(3)/3

    for (int ii = 0; ii < IR; ++ii) {
        const int i = ibase + ii;
        const float cx = sx[i], cy = sy[i], cz = sz[i];
        float p[4];
        float lsum = 0.0f;
        #pragma unroll
        for (int t = 0; t < 4; ++t) {
            int d0 = (int)(fabsf(cx - xs[t]) * 1000.0f);
            int d1 = (int)(fabsf(cy - ys[t]) * 1000.0f);
            int d2 = (int)(fabsf(cz - zs[t]) * 1000.0f);
            int cnt = val3(d0) + val3(d1) + val3(d2);
            p[t] = exp2f(-(float)cnt * kLog2_3_over3);
            lsum += p[t];
        }
        *(float4*)&pd_out[((size_t)(b * NN + i)) * NN + j0] =
            make_float4(p[0], p[1], p[2], p[3]);
        // wave reduce
        float x = lsum;
        #pragma unroll
        for (int off = 32; off > 0; off >>= 1) x += __shfl_xor(x, off, 64);
        if ((tid & 63) == 0) red[ii][tid >> 6] = x;
    }
    __syncthreads();
    if (tid < IR) {
        pdmean[b * NN + ibase + tid] =
            (red[tid][0] + red[tid][1] + red[tid][2] + red[tid][3]) * (1.0f / 1024.0f);
    }
}

// ---------------- Kernel B: encoder MLP + 3 GVP layers ----------------
#define GR 4
__global__ __launch_bounds__(64) void gvp_kernel(const float* __restrict__ s_in,
                           const float* __restrict__ v_in,
                           const float* __restrict__ enc_w1,
                           const float* __restrict__ enc_b1,
                           const float* __restrict__ enc_w2,
                           const float* __restrict__ enc_b2,
                           const float* __restrict__ scal_w,
                           const float* __restrict__ scal_b,
                           const float* __restrict__ vec_w,
                           const float* __restrict__ gate_w,
                           const float* __restrict__ gate_b,
                           const float* __restrict__ pdmean,
                           float* __restrict__ s_gvp,
                           float* __restrict__ v_out) {
    const int lane = threadIdx.x;          // 0..63
    const int rbase = blockIdx.x * GR;     // grid = 8192/GR

    __shared__ float sc[GR][80];           // [s(64) | vn(8)], padded
    __shared__ float vbuf[GR][24];
    __shared__ float vtb[GR][24];
    __shared__ float gg[GR][8];
    __shared__ float hid[GR][16];

    #pragma unroll
    for (int r = 0; r < GR; ++r) {
        const int row = rbase + r;
        sc[r][lane] = s_in[(size_t)row * 64 + lane];
        if (lane < 24) vbuf[r][lane] = v_in[(size_t)row * 24 + lane];
        if (lane < 16) {
            float pm = pdmean[row];
            hid[r][lane] = silu_f(pm * enc_w1[lane] + enc_b1[lane]);
        }
    }
    __syncthreads();
    #pragma unroll
    for (int r = 0; r < GR; ++r) {
        float acc = enc_b2[lane];
        #pragma unroll
        for (int h = 0; h < 16; ++h) acc += hid[r][h] * enc_w2[lane * 16 + h];
        sc[r][lane] += acc;
    }
    __syncthreads();

    for (int layer = 0; layer < 3; ++layer) {
        const bool act = layer < 2;
        if (lane < 8) {
            #pragma unroll
            for (int r = 0; r < GR; ++r) {
                float x = vbuf[r][lane * 3 + 0];
                float y = vbuf[r][lane * 3 + 1];
                float z = vbuf[r][lane * 3 + 2];
                sc[r][64 + lane] = sqrtf(x * x + y * y + z * z);
            }
        }
        __syncthreads();

        float sn[GR];
        {
            float4 w4[18];
            const float4* wr = (const float4*)(scal_w + ((size_t)layer * 64 + lane) * 72);
            #pragma unroll
            for (int k = 0; k < 18; ++k) w4[k] = wr[k];
            const float sb = scal_b[layer * 64 + lane];
            #pragma unroll
            for (int r = 0; r < GR; ++r) {
                const float4* sv = (const float4*)sc[r];
                float acc = sb;
                #pragma unroll
                for (int k = 0; k < 18; ++k) {
                    float4 s4 = sv[k];
                    acc += w4[k].x * s4.x + w4[k].y * s4.y + w4[k].z * s4.z + w4[k].w * s4.w;
                }
                sn[r] = acc;
            }
        }
        if (lane < 8) {
            float4 g4[18];
            const float4* gr_ = (const float4*)(gate_w + ((size_t)layer * 8 + lane) * 72);
            #pragma unroll
            for (int k = 0; k < 18; ++k) g4[k] = gr_[k];
            const float gb = gate_b[layer * 8 + lane];
            #pragma unroll
            for (int r = 0; r < GR; ++r) {
                const float4* sv = (const float4*)sc[r];
                float acc = gb;
                #pragma unroll
                for (int k = 0; k < 18; ++k) {
                    float4 s4 = sv[k];
                    acc += g4[k].x * s4.x + g4[k].y * s4.y + g4[k].z * s4.z + g4[k].w * s4.w;
                }
                gg[r][lane] = sigmoid_f(acc);
            }
        }
        if (lane < 24) {
            const int o = lane / 3;
            const int xc = lane - o * 3;
            const float* vw = vec_w + ((size_t)layer * 8 + o) * 8;
            float vwr[8];
            #pragma unroll
            for (int ii = 0; ii < 8; ++ii) vwr[ii] = vw[ii];
            #pragma unroll
            for (int r = 0; r < GR; ++r) {
                float acc = 0.0f;
                #pragma unroll
                for (int ii = 0; ii < 8; ++ii) acc += vwr[ii] * vbuf[r][ii * 3 + xc];
                vtb[r][lane] = acc;
            }
        }
        __syncthreads();

        #pragma unroll
        for (int r = 0; r < GR; ++r) {
            float val = act ? silu_f(sn[r]) : sn[r];
            sc[r][lane] = (layer > 0) ? (sc[r][lane] + val) : val;
        }
        if (lane < 24) {
            const int o = lane / 3;
            #pragma unroll
            for (int r = 0; r < GR; ++r) {
                float val = vtb[r][lane];
                if (act) {
                    float a = vtb[r][o * 3 + 0];
                    float bb2 = vtb[r][o * 3 + 1];
                    float c2 = vtb[r][o * 3 + 2];
                    val *= sigmoid_f(sqrtf(a * a + bb2 * bb2 + c2 * c2));
                }
                val *= gg[r][o];
                vbuf[r][lane] = (layer > 0) ? (vbuf[r][lane] + val) : val;
            }
        }
        __syncthreads();
    }

    #pragma unroll
    for (int r = 0; r < GR; ++r) {
        const int row = rbase + r;
        s_gvp[(size_t)row * 64 + lane] = sc[r][lane];
        if (lane < 24) v_out[(size_t)row * 24 + lane] = vbuf[r][lane];
    }
}

// ---------------- Kernel C: QKV projection (8 rows/block) ----------------
#define QROWS 8
__global__ __launch_bounds__(192) void qkv_kernel(const float* __restrict__ s_gvp,
                           const float* __restrict__ w,
                           const float* __restrict__ bias,
                           float* __restrict__ q,
                           float* __restrict__ k,
                           float* __restrict__ v) {
    const int tid = threadIdx.x;            // 0..191 = output col
    const int rbase = blockIdx.x * QROWS;   // grid 1024
    __shared__ float sl[QROWS][64];
    for (int idx = tid; idx < QROWS * 64; idx += 192)
        sl[idx >> 6][idx & 63] = s_gvp[(size_t)rbase * 64 + idx];
    __syncthreads();

    float4 w4[16];
    const float4* wr = (const float4*)(w + (size_t)tid * 64);
    #pragma unroll
    for (int kk = 0; kk < 16; ++kk) w4[kk] = wr[kk];
    const float bv = bias[tid];

    const int which = tid >> 6;
    const int e = tid & 63;
    const int h = e >> 4, d = e & 15;
    float* dst = (which == 0) ? q : (which == 1) ? k : v;

    #pragma unroll
    for (int r = 0; r < QROWS; ++r) {
        const float4* sv = (const float4*)sl[r];
        float acc = bv;
        #pragma unroll
        for (int kk = 0; kk < 16; ++kk) {
            float4 s4 = sv[kk];
            acc += w4[kk].x * s4.x + w4[kk].y * s4.y + w4[kk].z * s4.z + w4[kk].w * s4.w;
        }
        const int row = rbase + r;
        const int b = row >> 10, n = row & 1023;
        dst[(((size_t)(b * HH + h)) * NN + n) * HDD + d] = acc;
    }
}

// ---------------- Kernel D: flash attention, K-split x2, partials out ----------------
// Grid: (B*H) * (N/64) * 2 blocks, 256 threads.
// Block (bh, qt, ks): 64 queries x 512 keys (4 tiles of 128).
// Writes unnormalized acc + (m, l) partials.
__global__ __launch_bounds__(256, 4)
void attn_kernel(const float* __restrict__ q,
                 const float* __restrict__ k,
                 const float* __restrict__ v,
                 const float* __restrict__ pd,
                 float* __restrict__ po,   // [2][32768][16]
                 float* __restrict__ pm,   // [2][32768]
                 float* __restrict__ pl) { // [2][32768]
    const int ks = blockIdx.x & 1;
    const int qt = (blockIdx.x >> 1) & 15;
    const int bh = blockIdx.x >> 5;        // b*H + h
    const int b = bh >> 2;
    const int tid = threadIdx.x;
    const int kl = tid & 15;
    const int qg = tid >> 4;
    const int qbase = qt * 64 + qg * 4;

    // padded rows (16 -> 20 floats): 2-way bank alias (free)
    __shared__ float kt[128][20];
    __shared__ float vt[128][20];

    float qreg[4][16];
    const float* qb_ = q + ((size_t)bh * NN + qbase) * HDD;
    #pragma unroll
    for (int i = 0; i < 4; ++i) {
        #pragma unroll
        for (int d = 0; d < 16; d += 4) {
            float4 t4 = *(const float4*)(qb_ + i * 16 + d);
            qreg[i][d] = t4.x; qreg[i][d+1] = t4.y; qreg[i][d+2] = t4.z; qreg[i][d+3] = t4.w;
        }
    }
    const float* pdr0 = pd + ((size_t)b * NN + qbase) * NN + ks * 512;

    float acc[4][16];
    #pragma unroll
    for (int i = 0; i < 4; ++i)
        #pragma unroll
        for (int d = 0; d < 16; ++d) acc[i][d] = 0.0f;
    float mrun[4] = {-INFINITY, -INFINITY, -INFINITY, -INFINITY};
    float lrun[4] = {0.0f, 0.0f, 0.0f, 0.0f};

    const float* kbase = k + ((size_t)bh * NN + ks * 512) * HDD;
    const float* vbase = v + ((size_t)bh * NN + ks * 512) * HDD;
    const float kLog2e = 1.44269504f;

    for (int tile = 0; tile < 4; ++tile) {
        __syncthreads();
        {
            const float4* kg = (const float4*)(kbase + (size_t)tile * 128 * 16);
            const float4* vg = (const float4*)(vbase + (size_t)tile * 128 * 16);
            int c0 = tid, c1 = tid + 256;
            int r0 = c0 >> 2, s0 = c0 & 3;
            int r1 = c1 >> 2, s1 = c1 & 3;
            *(float4*)&kt[r0][s0 * 4] = kg[c0];
            *(float4*)&kt[r1][s1 * 4] = kg[c1];
            *(float4*)&vt[r0][s0 * 4] = vg[c0];
            *(float4*)&vt[r1][s1 * 4] = vg[c1];
        }
        __syncthreads();

        float sc[4][8];
        #pragma unroll
        for (int m = 0; m < 8; ++m) {
            const int jt = kl + 16 * m;
            float kr[16];
            #pragma unroll
            for (int d = 0; d < 16; d += 4) {
                float4 t4 = *(const float4*)&kt[jt][d];
                kr[d] = t4.x; kr[d+1] = t4.y; kr[d+2] = t4.z; kr[d+3] = t4.w;
            }
            const int j = tile * 128 + jt;
            #pragma unroll
            for (int i = 0; i < 4; ++i) {
                float a = 0.0f;
                #pragma unroll
                for (int d = 0; d < 16; ++d) a += qreg[i][d] * kr[d];
                sc[i][m] = a * 0.25f - pdr0[(size_t)i * NN + j];
            }
        }

        #pragma unroll
        for (int i = 0; i < 4; ++i) {
            float tmax = sc[i][0];
            #pragma unroll
            for (int m = 1; m < 8; ++m) tmax = fmaxf(tmax, sc[i][m]);
            #pragma unroll
            for (int w = 1; w < 16; w <<= 1) tmax = fmaxf(tmax, __shfl_xor(tmax, w, 16));
            float mnew = fmaxf(mrun[i], tmax);
            float scale = exp2f((mrun[i] - mnew) * kLog2e);
            mrun[i] = mnew;
            lrun[i] *= scale;
            #pragma unroll
            for (int d = 0; d < 16; ++d) acc[i][d] *= scale;
            float ls = 0.0f;
            #pragma unroll
            for (int m = 0; m < 8; ++m) {
                float p = exp2f((sc[i][m] - mnew) * kLog2e);
                sc[i][m] = p;
                ls += p;
            }
            lrun[i] += ls;
        }

        #pragma unroll
        for (int m = 0; m < 8; ++m) {
            const int jt = kl + 16 * m;
            float vr[16];
            #pragma unroll
            for (int d = 0; d < 16; d += 4) {
                float4 t4 = *(const float4*)&vt[jt][d];
                vr[d] = t4.x; vr[d+1] = t4.y; vr[d+2] = t4.z; vr[d+3] = t4.w;
            }
            #pragma unroll
            for (int i = 0; i < 4; ++i) {
                const float p = sc[i][m];
                #pragma unroll
                for (int d = 0; d < 16; ++d) acc[i][d] += p * vr[d];
            }
        }
    }

    // reduce l and acc across the 16 kl lanes; write partials
    #pragma unroll
    for (int i = 0; i < 4; ++i) {
        float l = lrun[i];
        #pragma unroll
        for (int w = 1; w < 16; w <<= 1) l += __shfl_xor(l, w, 16);
        lrun[i] = l;
    }
    float outv[4] = {0.0f, 0.0f, 0.0f, 0.0f};
    #pragma unroll
    for (int i = 0; i < 4; ++i) {
        #pragma unroll
        for (int d = 0; d < 16; ++d) {
            float a = acc[i][d];
            #pragma unroll
            for (int w = 1; w < 16; w <<= 1) a += __shfl_xor(a, w, 16);
            if (kl == d) outv[i] = a;
        }
    }
    const size_t sbase = (size_t)ks * 32768 + (size_t)bh * NN + qbase;
    #pragma unroll
    for (int i = 0; i < 4; ++i) {
        po[(sbase + i) * 16 + kl] = outv[i];
        if (kl == 0) {
            pm[sbase + i] = mrun[i];
            pl[sbase + i] = lrun[i];
        }
    }
}

// ---------------- Kernel E: merge K-split partials + out projection + residual ----------------
#define OROWS 16
__global__ __launch_bounds__(256) void outproj_kernel(const float* __restrict__ s_gvp,
                               const float* __restrict__ po,
                               const float* __restrict__ pm,
                               const float* __restrict__ pl,
                               const float* __restrict__ w,
                               const float* __restrict__ bias,
                               float* __restrict__ s_out) {
    const int tid = threadIdx.x;
    const int col = tid & 63;
    const int wq = tid >> 6;                // wave id 0..3
    const int rbase = blockIdx.x * OROWS;   // grid 512
    __shared__ float ol[OROWS][64];
    const float kLog2e = 1.44269504f;
    for (int idx = tid; idx < OROWS * 64; idx += 256) {
        const int r = idx >> 6;
        const int c = idx & 63;
        const int row = rbase + r;
        const int b = row >> 10, n = row & 1023;
        const int h = c >> 4, d = c & 15;
        const size_t i2 = (size_t)(b * HH + h) * NN + n;
        float m0 = pm[i2], m1 = pm[32768 + i2];
        float l0 = pl[i2], l1 = pl[32768 + i2];
        float a0 = po[i2 * 16 + d], a1 = po[(32768 + i2) * 16 + d];
        float mm = fmaxf(m0, m1);
        float e0 = exp2f((m0 - mm) * kLog2e);
        float e1 = exp2f((m1 - mm) * kLog2e);
        ol[r][c] = (a0 * e0 + a1 * e1) / (l0 * e0 + l1 * e1);
    }
    __syncthreads();

    float4 w4[16];
    const float4* wr = (const float4*)(w + (size_t)col * 64);
    #pragma unroll
    for (int kk = 0; kk < 16; ++kk) w4[kk] = wr[kk];
    const float bv = bias[col];

    #pragma unroll
    for (int rr = 0; rr < OROWS / 4; ++rr) {
        const int r = wq * (OROWS / 4) + rr;
        const float4* sv = (const float4*)ol[r];
        float acc = bv;
        #pragma unroll
        for (int kk = 0; kk < 16; ++kk) {
            float4 s4 = sv[kk];
            acc += w4[kk].x * s4.x + w4[kk].y * s4.y + w4[kk].z * s4.z + w4[kk].w * s4.w;
        }
        const int row = rbase + r;
        s_out[(size_t)row * 64 + col] = s_gvp[(size_t)row * 64 + col] + acc;
    }
}

extern "C" void kernel_launch(void* const* d_in, const int* in_sizes, int n_in,
                              void* d_out, int out_size, void* d_ws, size_t ws_size,
                              hipStream_t stream) {
    const float* s_in      = (const float*)d_in[0];
    const float* v_in      = (const float*)d_in[1];
    const float* coords    = (const float*)d_in[2];
    const float* enc_w1    = (const float*)d_in[3];
    const float* enc_b1    = (const float*)d_in[4];
    const float* enc_w2    = (const float*)d_in[5];
    const float* enc_b2    = (const float*)d_in[6];
    const float* scal_w    = (const float*)d_in[7];
    const float* scal_b    = (const float*)d_in[8];
    const float* vec_w     = (const float*)d_in[9];
    const float* gate_w    = (const float*)d_in[10];
    const float* gate_b    = (const float*)d_in[11];
    const float* in_proj_w = (const float*)d_in[12];
    const float* in_proj_b = (const float*)d_in[13];
    const float* out_proj_w= (const float*)d_in[14];
    const float* out_proj_b= (const float*)d_in[15];

    float* out_s  = (float*)d_out + OUT_S_OFF;
    float* out_v  = (float*)d_out + OUT_V_OFF;
    float* out_pd = (float*)d_out + OUT_PD_OFF;

    // ws layout (floats): pdmean[8192] | s_gvp[524288] | q | k | v [524288 ea]
    //                     | po[2*32768*16] | pm[2*32768] | pl[2*32768]
    float* ws      = (float*)d_ws;
    float* pdmean  = ws;
    float* s_gvp   = ws + 8192;
    float* qb      = s_gvp + 524288;
    float* kb      = qb + 524288;
    float* vvb     = kb + 524288;
    float* po      = vvb + 524288;
    float* pm      = po + 2 * 32768 * 16;
    float* pl      = pm + 2 * 32768;

    const int rows = BB * NN;  // 8192

    pd_kernel<<<BB * (NN / IR), 256, 0, stream>>>(coords, out_pd, pdmean);
    gvp_kernel<<<rows / GR, 64, 0, stream>>>(s_in, v_in, enc_w1, enc_b1, enc_w2, enc_b2,
                                             scal_w, scal_b, vec_w, gate_w, gate_b,
                                             pdmean, s_gvp, out_v);
    qkv_kernel<<<rows / QROWS, 192, 0, stream>>>(s_gvp, in_proj_w, in_proj_b, qb, kb, vvb);
    attn_kernel<<<BB * HH * (NN / 64) * 2, 256, 0, stream>>>(qb, kb, vvb, out_pd, po, pm, pl);
    outproj_kernel<<<rows / OROWS, 256, 0, stream>>>(s_gvp, po, pm, pl,
                                                     out_proj_w, out_proj_b, out_s);
}

// Round 5
// 190.901 us; speedup vs baseline: 1.7530x; 1.7530x over previous
//
#include <hip/hip_runtime.h>
#include <hip/hip_bf16.h>
#include <math.h>

// Problem constants
#define BB 8
#define NN 1024
#define SS 64
#define VCC 8
#define EE 64
#define HH 4
#define HDD 16

// d_out layout: s (B*N*S=524288) | v (B*N*VC*3=196608) | pd (B*N*N=8388608)
#define OUT_S_OFF 0
#define OUT_V_OFF 524288
#define OUT_PD_OFF 720896

// 3-adic valuation capped at 10, zero for d==0
__device__ __forceinline__ int val3(int d) {
    int c = 0;
    unsigned ud = (unsigned)d;
    c += (ud % 3u == 0u);
    c += (ud % 9u == 0u);
    c += (ud % 27u == 0u);
    c += (ud % 81u == 0u);
    c += (ud % 243u == 0u);
    c += (ud % 729u == 0u);
    c += (ud % 2187u == 0u);
    c += (ud % 6561u == 0u);
    c += (ud % 19683u == 0u);
    c += (ud % 59049u == 0u);
    return d > 0 ? c : 0;
}

__device__ __forceinline__ float silu_f(float x) {
    return x / (1.0f + expf(-x));
}
__device__ __forceinline__ float sigmoid_f(float x) {
    return 1.0f / (1.0f + expf(-x));
}

// ---------------- Kernel A: pd matrix + row means ----------------
// Block = 16 i-rows x 1024 j. coords staged once in LDS (SoA); per-thread
// j-coords in registers reused across the 16 rows. Grid = B * 64 = 512.
#define IR 16
__global__ __launch_bounds__(256) void pd_kernel(const float* __restrict__ coords,
                                                 float* __restrict__ pd_out,
                                                 float* __restrict__ pdmean) {
    const int bi = blockIdx.x;            // b*64 + itile
    const int b = bi >> 6;
    const int ibase = (bi & 63) * IR;
    const int tid = threadIdx.x;
    const float* cb = coords + (size_t)b * NN * 3;

    __shared__ float sx[1024];
    __shared__ float sy[1024];
    __shared__ float sz[1024];
    __shared__ float red[IR][4];

    for (int idx = tid; idx < 3072; idx += 256) {
        float v = cb[idx];
        int j = idx / 3;
        int c = idx - j * 3;
        float* dst = (c == 0) ? sx : (c == 1) ? sy : sz;
        dst[j] = v;
    }
    __syncthreads();

    const int j0 = tid * 4;
    float4 x4 = *(const float4*)&sx[j0];
    float4 y4 = *(const float4*)&sy[j0];
    float4 z4 = *(const float4*)&sz[j0];
    float xs[4] = {x4.x, x4.y, x4.z, x4.w};
    float ys[4] = {y4.x, y4.y, y4.z, y4.w};
    float zs[4] = {z4.x, z4.y, z4.z, z4.w};

    const float kLog2_3_over3 = 0.5283208335737187f;  // log2(3)/3

    for (int ii = 0; ii < IR; ++ii) {
        const int i = ibase + ii;
        const float cx = sx[i], cy = sy[i], cz = sz[i];
        float p[4];
        float lsum = 0.0f;
        #pragma unroll
        for (int t = 0; t < 4; ++t) {
            int d0 = (int)(fabsf(cx - xs[t]) * 1000.0f);
            int d1 = (int)(fabsf(cy - ys[t]) * 1000.0f);
            int d2 = (int)(fabsf(cz - zs[t]) * 1000.0f);
            int cnt = val3(d0) + val3(d1) + val3(d2);
            p[t] = exp2f(-(float)cnt * kLog2_3_over3);
            lsum += p[t];
        }
        *(float4*)&pd_out[((size_t)(b * NN + i)) * NN + j0] =
            make_float4(p[0], p[1], p[2], p[3]);
        // wave reduce
        float x = lsum;
        #pragma unroll
        for (int off = 32; off > 0; off >>= 1) x += __shfl_xor(x, off, 64);
        if ((tid & 63) == 0) red[ii][tid >> 6] = x;
    }
    __syncthreads();
    if (tid < IR) {
        pdmean[b * NN + ibase + tid] =
            (red[tid][0] + red[tid][1] + red[tid][2] + red[tid][3]) * (1.0f / 1024.0f);
    }
}

// ---------------- Kernel B: encoder MLP + 3 GVP layers ----------------
#define GR 4
__global__ __launch_bounds__(64) void gvp_kernel(const float* __restrict__ s_in,
                           const float* __restrict__ v_in,
                           const float* __restrict__ enc_w1,
                           const float* __restrict__ enc_b1,
                           const float* __restrict__ enc_w2,
                           const float* __restrict__ enc_b2,
                           const float* __restrict__ scal_w,
                           const float* __restrict__ scal_b,
                           const float* __restrict__ vec_w,
                           const float* __restrict__ gate_w,
                           const float* __restrict__ gate_b,
                           const float* __restrict__ pdmean,
                           float* __restrict__ s_gvp,
                           float* __restrict__ v_out) {
    const int lane = threadIdx.x;          // 0..63
    const int rbase = blockIdx.x * GR;     // grid = 8192/GR

    __shared__ float sc[GR][80];           // [s(64) | vn(8)], padded
    __shared__ float vbuf[GR][24];
    __shared__ float vtb[GR][24];
    __shared__ float gg[GR][8];
    __shared__ float hid[GR][16];

    #pragma unroll
    for (int r = 0; r < GR; ++r) {
        const int row = rbase + r;
        sc[r][lane] = s_in[(size_t)row * 64 + lane];
        if (lane < 24) vbuf[r][lane] = v_in[(size_t)row * 24 + lane];
        if (lane < 16) {
            float pm = pdmean[row];
            hid[r][lane] = silu_f(pm * enc_w1[lane] + enc_b1[lane]);
        }
    }
    __syncthreads();
    #pragma unroll
    for (int r = 0; r < GR; ++r) {
        float acc = enc_b2[lane];
        #pragma unroll
        for (int h = 0; h < 16; ++h) acc += hid[r][h] * enc_w2[lane * 16 + h];
        sc[r][lane] += acc;
    }
    __syncthreads();

    for (int layer = 0; layer < 3; ++layer) {
        const bool act = layer < 2;
        if (lane < 8) {
            #pragma unroll
            for (int r = 0; r < GR; ++r) {
                float x = vbuf[r][lane * 3 + 0];
                float y = vbuf[r][lane * 3 + 1];
                float z = vbuf[r][lane * 3 + 2];
                sc[r][64 + lane] = sqrtf(x * x + y * y + z * z);
            }
        }
        __syncthreads();

        float sn[GR];
        {
            float4 w4[18];
            const float4* wr = (const float4*)(scal_w + ((size_t)layer * 64 + lane) * 72);
            #pragma unroll
            for (int k = 0; k < 18; ++k) w4[k] = wr[k];
            const float sb = scal_b[layer * 64 + lane];
            #pragma unroll
            for (int r = 0; r < GR; ++r) {
                const float4* sv = (const float4*)sc[r];
                float acc = sb;
                #pragma unroll
                for (int k = 0; k < 18; ++k) {
                    float4 s4 = sv[k];
                    acc += w4[k].x * s4.x + w4[k].y * s4.y + w4[k].z * s4.z + w4[k].w * s4.w;
                }
                sn[r] = acc;
            }
        }
        if (lane < 8) {
            float4 g4[18];
            const float4* gr_ = (const float4*)(gate_w + ((size_t)layer * 8 + lane) * 72);
            #pragma unroll
            for (int k = 0; k < 18; ++k) g4[k] = gr_[k];
            const float gb = gate_b[layer * 8 + lane];
            #pragma unroll
            for (int r = 0; r < GR; ++r) {
                const float4* sv = (const float4*)sc[r];
                float acc = gb;
                #pragma unroll
                for (int k = 0; k < 18; ++k) {
                    float4 s4 = sv[k];
                    acc += g4[k].x * s4.x + g4[k].y * s4.y + g4[k].z * s4.z + g4[k].w * s4.w;
                }
                gg[r][lane] = sigmoid_f(acc);
            }
        }
        if (lane < 24) {
            const int o = lane / 3;
            const int xc = lane - o * 3;
            const float* vw = vec_w + ((size_t)layer * 8 + o) * 8;
            float vwr[8];
            #pragma unroll
            for (int ii = 0; ii < 8; ++ii) vwr[ii] = vw[ii];
            #pragma unroll
            for (int r = 0; r < GR; ++r) {
                float acc = 0.0f;
                #pragma unroll
                for (int ii = 0; ii < 8; ++ii) acc += vwr[ii] * vbuf[r][ii * 3 + xc];
                vtb[r][lane] = acc;
            }
        }
        __syncthreads();

        #pragma unroll
        for (int r = 0; r < GR; ++r) {
            float val = act ? silu_f(sn[r]) : sn[r];
            sc[r][lane] = (layer > 0) ? (sc[r][lane] + val) : val;
        }
        if (lane < 24) {
            const int o = lane / 3;
            #pragma unroll
            for (int r = 0; r < GR; ++r) {
                float val = vtb[r][lane];
                if (act) {
                    float a = vtb[r][o * 3 + 0];
                    float bb2 = vtb[r][o * 3 + 1];
                    float c2 = vtb[r][o * 3 + 2];
                    val *= sigmoid_f(sqrtf(a * a + bb2 * bb2 + c2 * c2));
                }
                val *= gg[r][o];
                vbuf[r][lane] = (layer > 0) ? (vbuf[r][lane] + val) : val;
            }
        }
        __syncthreads();
    }

    #pragma unroll
    for (int r = 0; r < GR; ++r) {
        const int row = rbase + r;
        s_gvp[(size_t)row * 64 + lane] = sc[r][lane];
        if (lane < 24) v_out[(size_t)row * 24 + lane] = vbuf[r][lane];
    }
}

// ---------------- Kernel C: QKV projection (8 rows/block) ----------------
#define QROWS 8
__global__ __launch_bounds__(192) void qkv_kernel(const float* __restrict__ s_gvp,
                           const float* __restrict__ w,
                           const float* __restrict__ bias,
                           float* __restrict__ q,
                           float* __restrict__ k,
                           float* __restrict__ v) {
    const int tid = threadIdx.x;            // 0..191 = output col
    const int rbase = blockIdx.x * QROWS;   // grid 1024
    __shared__ float sl[QROWS][64];
    for (int idx = tid; idx < QROWS * 64; idx += 192)
        sl[idx >> 6][idx & 63] = s_gvp[(size_t)rbase * 64 + idx];
    __syncthreads();

    float4 w4[16];
    const float4* wr = (const float4*)(w + (size_t)tid * 64);
    #pragma unroll
    for (int kk = 0; kk < 16; ++kk) w4[kk] = wr[kk];
    const float bv = bias[tid];

    const int which = tid >> 6;
    const int e = tid & 63;
    const int h = e >> 4, d = e & 15;
    float* dst = (which == 0) ? q : (which == 1) ? k : v;

    #pragma unroll
    for (int r = 0; r < QROWS; ++r) {
        const float4* sv = (const float4*)sl[r];
        float acc = bv;
        #pragma unroll
        for (int kk = 0; kk < 16; ++kk) {
            float4 s4 = sv[kk];
            acc += w4[kk].x * s4.x + w4[kk].y * s4.y + w4[kk].z * s4.z + w4[kk].w * s4.w;
        }
        const int row = rbase + r;
        const int b = row >> 10, n = row & 1023;
        dst[(((size_t)(b * HH + h)) * NN + n) * HDD + d] = acc;
    }
}

// ---------------- Kernel D: flash attention, K-split x2, partials out ----------------
// Grid: (B*H) * (N/64) * 2 blocks, 256 threads.
// Block (bh, qt, ks): 64 queries x 512 keys (4 tiles of 128).
// Writes unnormalized acc + (m, l) partials.
// NOTE: __launch_bounds__(256,2) — NOT (256,4): the thread state is
// qreg[4][16]+acc[4][16] = 128 floats; forcing 4 waves/SIMD caps VGPR at 64
// and spills everything to scratch (R4: 365MB fetch + 440MB write, 3x slower).
// At 128 VGPR the HW still co-schedules 4 blocks/CU (m69 occupancy steps).
__global__ __launch_bounds__(256, 2)
void attn_kernel(const float* __restrict__ q,
                 const float* __restrict__ k,
                 const float* __restrict__ v,
                 const float* __restrict__ pd,
                 float* __restrict__ po,   // [2][32768][16]
                 float* __restrict__ pm,   // [2][32768]
                 float* __restrict__ pl) { // [2][32768]
    const int ks = blockIdx.x & 1;
    const int qt = (blockIdx.x >> 1) & 15;
    const int bh = blockIdx.x >> 5;        // b*H + h
    const int b = bh >> 2;
    const int tid = threadIdx.x;
    const int kl = tid & 15;
    const int qg = tid >> 4;
    const int qbase = qt * 64 + qg * 4;

    // padded rows (16 -> 20 floats): 2-way bank alias (free)
    __shared__ float kt[128][20];
    __shared__ float vt[128][20];

    float qreg[4][16];
    const float* qb_ = q + ((size_t)bh * NN + qbase) * HDD;
    #pragma unroll
    for (int i = 0; i < 4; ++i) {
        #pragma unroll
        for (int d = 0; d < 16; d += 4) {
            float4 t4 = *(const float4*)(qb_ + i * 16 + d);
            qreg[i][d] = t4.x; qreg[i][d+1] = t4.y; qreg[i][d+2] = t4.z; qreg[i][d+3] = t4.w;
        }
    }
    const float* pdr0 = pd + ((size_t)b * NN + qbase) * NN + ks * 512;

    float acc[4][16];
    #pragma unroll
    for (int i = 0; i < 4; ++i)
        #pragma unroll
        for (int d = 0; d < 16; ++d) acc[i][d] = 0.0f;
    float mrun[4] = {-INFINITY, -INFINITY, -INFINITY, -INFINITY};
    float lrun[4] = {0.0f, 0.0f, 0.0f, 0.0f};

    const float* kbase = k + ((size_t)bh * NN + ks * 512) * HDD;
    const float* vbase = v + ((size_t)bh * NN + ks * 512) * HDD;
    const float kLog2e = 1.44269504f;

    for (int tile = 0; tile < 4; ++tile) {
        __syncthreads();
        {
            const float4* kg = (const float4*)(kbase + (size_t)tile * 128 * 16);
            const float4* vg = (const float4*)(vbase + (size_t)tile * 128 * 16);
            int c0 = tid, c1 = tid + 256;
            int r0 = c0 >> 2, s0 = c0 & 3;
            int r1 = c1 >> 2, s1 = c1 & 3;
            *(float4*)&kt[r0][s0 * 4] = kg[c0];
            *(float4*)&kt[r1][s1 * 4] = kg[c1];
            *(float4*)&vt[r0][s0 * 4] = vg[c0];
            *(float4*)&vt[r1][s1 * 4] = vg[c1];
        }
        __syncthreads();

        float sc[4][8];
        #pragma unroll
        for (int m = 0; m < 8; ++m) {
            const int jt = kl + 16 * m;
            float kr[16];
            #pragma unroll
            for (int d = 0; d < 16; d += 4) {
                float4 t4 = *(const float4*)&kt[jt][d];
                kr[d] = t4.x; kr[d+1] = t4.y; kr[d+2] = t4.z; kr[d+3] = t4.w;
            }
            const int j = tile * 128 + jt;
            #pragma unroll
            for (int i = 0; i < 4; ++i) {
                float a = 0.0f;
                #pragma unroll
                for (int d = 0; d < 16; ++d) a += qreg[i][d] * kr[d];
                sc[i][m] = a * 0.25f - pdr0[(size_t)i * NN + j];
            }
        }

        #pragma unroll
        for (int i = 0; i < 4; ++i) {
            float tmax = sc[i][0];
            #pragma unroll
            for (int m = 1; m < 8; ++m) tmax = fmaxf(tmax, sc[i][m]);
            #pragma unroll
            for (int w = 1; w < 16; w <<= 1) tmax = fmaxf(tmax, __shfl_xor(tmax, w, 16));
            float mnew = fmaxf(mrun[i], tmax);
            float scale = exp2f((mrun[i] - mnew) * kLog2e);
            mrun[i] = mnew;
            lrun[i] *= scale;
            #pragma unroll
            for (int d = 0; d < 16; ++d) acc[i][d] *= scale;
            float ls = 0.0f;
            #pragma unroll
            for (int m = 0; m < 8; ++m) {
                float p = exp2f((sc[i][m] - mnew) * kLog2e);
                sc[i][m] = p;
                ls += p;
            }
            lrun[i] += ls;
        }

        #pragma unroll
        for (int m = 0; m < 8; ++m) {
            const int jt = kl + 16 * m;
            float vr[16];
            #pragma unroll
            for (int d = 0; d < 16; d += 4) {
                float4 t4 = *(const float4*)&vt[jt][d];
                vr[d] = t4.x; vr[d+1] = t4.y; vr[d+2] = t4.z; vr[d+3] = t4.w;
            }
            #pragma unroll
            for (int i = 0; i < 4; ++i) {
                const float p = sc[i][m];
                #pragma unroll
                for (int d = 0; d < 16; ++d) acc[i][d] += p * vr[d];
            }
        }
    }

    // reduce l and acc across the 16 kl lanes; write partials
    #pragma unroll
    for (int i = 0; i < 4; ++i) {
        float l = lrun[i];
        #pragma unroll
        for (int w = 1; w < 16; w <<= 1) l += __shfl_xor(l, w, 16);
        lrun[i] = l;
    }
    float outv[4] = {0.0f, 0.0f, 0.0f, 0.0f};
    #pragma unroll
    for (int i = 0; i < 4; ++i) {
        #pragma unroll
        for (int d = 0; d < 16; ++d) {
            float a = acc[i][d];
            #pragma unroll
            for (int w = 1; w < 16; w <<= 1) a += __shfl_xor(a, w, 16);
            if (kl == d) outv[i] = a;
        }
    }
    const size_t sbase = (size_t)ks * 32768 + (size_t)bh * NN + qbase;
    #pragma unroll
    for (int i = 0; i < 4; ++i) {
        po[(sbase + i) * 16 + kl] = outv[i];
        if (kl == 0) {
            pm[sbase + i] = mrun[i];
            pl[sbase + i] = lrun[i];
        }
    }
}

// ---------------- Kernel E: merge K-split partials + out projection + residual ----------------
#define OROWS 16
__global__ __launch_bounds__(256) void outproj_kernel(const float* __restrict__ s_gvp,
                               const float* __restrict__ po,
                               const float* __restrict__ pm,
                               const float* __restrict__ pl,
                               const float* __restrict__ w,
                               const float* __restrict__ bias,
                               float* __restrict__ s_out) {
    const int tid = threadIdx.x;
    const int col = tid & 63;
    const int wq = tid >> 6;                // wave id 0..3
    const int rbase = blockIdx.x * OROWS;   // grid 512
    __shared__ float ol[OROWS][64];
    const float kLog2e = 1.44269504f;
    for (int idx = tid; idx < OROWS * 64; idx += 256) {
        const int r = idx >> 6;
        const int c = idx & 63;
        const int row = rbase + r;
        const int b = row >> 10, n = row & 1023;
        const int h = c >> 4, d = c & 15;
        const size_t i2 = (size_t)(b * HH + h) * NN + n;
        float m0 = pm[i2], m1 = pm[32768 + i2];
        float l0 = pl[i2], l1 = pl[32768 + i2];
        float a0 = po[i2 * 16 + d], a1 = po[(32768 + i2) * 16 + d];
        float mm = fmaxf(m0, m1);
        float e0 = exp2f((m0 - mm) * kLog2e);
        float e1 = exp2f((m1 - mm) * kLog2e);
        ol[r][c] = (a0 * e0 + a1 * e1) / (l0 * e0 + l1 * e1);
    }
    __syncthreads();

    float4 w4[16];
    const float4* wr = (const float4*)(w + (size_t)col * 64);
    #pragma unroll
    for (int kk = 0; kk < 16; ++kk) w4[kk] = wr[kk];
    const float bv = bias[col];

    #pragma unroll
    for (int rr = 0; rr < OROWS / 4; ++rr) {
        const int r = wq * (OROWS / 4) + rr;
        const float4* sv = (const float4*)ol[r];
        float acc = bv;
        #pragma unroll
        for (int kk = 0; kk < 16; ++kk) {
            float4 s4 = sv[kk];
            acc += w4[kk].x * s4.x + w4[kk].y * s4.y + w4[kk].z * s4.z + w4[kk].w * s4.w;
        }
        const int row = rbase + r;
        s_out[(size_t)row * 64 + col] = s_gvp[(size_t)row * 64 + col] + acc;
    }
}

extern "C" void kernel_launch(void* const* d_in, const int* in_sizes, int n_in,
                              void* d_out, int out_size, void* d_ws, size_t ws_size,
                              hipStream_t stream) {
    const float* s_in      = (const float*)d_in[0];
    const float* v_in      = (const float*)d_in[1];
    const float* coords    = (const float*)d_in[2];
    const float* enc_w1    = (const float*)d_in[3];
    const float* enc_b1    = (const float*)d_in[4];
    const float* enc_w2    = (const float*)d_in[5];
    const float* enc_b2    = (const float*)d_in[6];
    const float* scal_w    = (const float*)d_in[7];
    const float* scal_b    = (const float*)d_in[8];
    const float* vec_w     = (const float*)d_in[9];
    const float* gate_w    = (const float*)d_in[10];
    const float* gate_b    = (const float*)d_in[11];
    const float* in_proj_w = (const float*)d_in[12];
    const float* in_proj_b = (const float*)d_in[13];
    const float* out_proj_w= (const float*)d_in[14];
    const float* out_proj_b= (const float*)d_in[15];

    float* out_s  = (float*)d_out + OUT_S_OFF;
    float* out_v  = (float*)d_out + OUT_V_OFF;
    float* out_pd = (float*)d_out + OUT_PD_OFF;

    // ws layout (floats): pdmean[8192] | s_gvp[524288] | q | k | v [524288 ea]
    //                     | po[2*32768*16] | pm[2*32768] | pl[2*32768]
    float* ws      = (float*)d_ws;
    float* pdmean  = ws;
    float* s_gvp   = ws + 8192;
    float* qb      = s_gvp + 524288;
    float* kb      = qb + 524288;
    float* vvb     = kb + 524288;
    float* po      = vvb + 524288;
    float* pm      = po + 2 * 32768 * 16;
    float* pl      = pm + 2 * 32768;

    const int rows = BB * NN;  // 8192

    pd_kernel<<<BB * (NN / IR), 256, 0, stream>>>(coords, out_pd, pdmean);
    gvp_kernel<<<rows / GR, 64, 0, stream>>>(s_in, v_in, enc_w1, enc_b1, enc_w2, enc_b2,
                                             scal_w, scal_b, vec_w, gate_w, gate_b,
                                             pdmean, s_gvp, out_v);
    qkv_kernel<<<rows / QROWS, 192, 0, stream>>>(s_gvp, in_proj_w, in_proj_b, qb, kb, vvb);
    attn_kernel<<<BB * HH * (NN / 64) * 2, 256, 0, stream>>>(qb, kb, vvb, out_pd, po, pm, pl);
    outproj_kernel<<<rows / OROWS, 256, 0, stream>>>(s_gvp, po, pm, pl,
                                                     out_proj_w, out_proj_b, out_s);
}

// Round 6
// 176.075 us; speedup vs baseline: 1.9006x; 1.0842x over previous
//
#include <hip/hip_runtime.h>
#include <hip/hip_bf16.h>
#include <math.h>

// Problem constants
#define BB 8
#define NN 1024
#define SS 64
#define VCC 8
#define EE 64
#define HH 4
#define HDD 16

// d_out layout: s (B*N*S=524288) | v (B*N*VC*3=196608) | pd (B*N*N=8388608)
#define OUT_S_OFF 0
#define OUT_V_OFF 524288
#define OUT_PD_OFF 720896

// 3-adic valuation capped at 10, zero for d==0
__device__ __forceinline__ int val3(int d) {
    int c = 0;
    unsigned ud = (unsigned)d;
    c += (ud % 3u == 0u);
    c += (ud % 9u == 0u);
    c += (ud % 27u == 0u);
    c += (ud % 81u == 0u);
    c += (ud % 243u == 0u);
    c += (ud % 729u == 0u);
    c += (ud % 2187u == 0u);
    c += (ud % 6561u == 0u);
    c += (ud % 19683u == 0u);
    c += (ud % 59049u == 0u);
    return d > 0 ? c : 0;
}

__device__ __forceinline__ float silu_f(float x) {
    return x / (1.0f + expf(-x));
}
__device__ __forceinline__ float sigmoid_f(float x) {
    return 1.0f / (1.0f + expf(-x));
}

// ---------------- Kernel A: pd matrix + row means ----------------
// Block = 16 i-rows x 1024 j. coords staged once in LDS (SoA); per-thread
// j-coords in registers reused across the 16 rows. Grid = B * 64 = 512.
#define IR 16
__global__ __launch_bounds__(256) void pd_kernel(const float* __restrict__ coords,
                                                 float* __restrict__ pd_out,
                                                 float* __restrict__ pdmean) {
    const int bi = blockIdx.x;            // b*64 + itile
    const int b = bi >> 6;
    const int ibase = (bi & 63) * IR;
    const int tid = threadIdx.x;
    const float* cb = coords + (size_t)b * NN * 3;

    __shared__ float sx[1024];
    __shared__ float sy[1024];
    __shared__ float sz[1024];
    __shared__ float red[IR][4];

    for (int idx = tid; idx < 3072; idx += 256) {
        float v = cb[idx];
        int j = idx / 3;
        int c = idx - j * 3;
        float* dst = (c == 0) ? sx : (c == 1) ? sy : sz;
        dst[j] = v;
    }
    __syncthreads();

    const int j0 = tid * 4;
    float4 x4 = *(const float4*)&sx[j0];
    float4 y4 = *(const float4*)&sy[j0];
    float4 z4 = *(const float4*)&sz[j0];
    float xs[4] = {x4.x, x4.y, x4.z, x4.w};
    float ys[4] = {y4.x, y4.y, y4.z, y4.w};
    float zs[4] = {z4.x, z4.y, z4.z, z4.w};

    const float kLog2_3_over3 = 0.5283208335737187f;  // log2(3)/3

    for (int ii = 0; ii < IR; ++ii) {
        const int i = ibase + ii;
        const float cx = sx[i], cy = sy[i], cz = sz[i];
        float p[4];
        float lsum = 0.0f;
        #pragma unroll
        for (int t = 0; t < 4; ++t) {
            int d0 = (int)(fabsf(cx - xs[t]) * 1000.0f);
            int d1 = (int)(fabsf(cy - ys[t]) * 1000.0f);
            int d2 = (int)(fabsf(cz - zs[t]) * 1000.0f);
            int cnt = val3(d0) + val3(d1) + val3(d2);
            p[t] = exp2f(-(float)cnt * kLog2_3_over3);
            lsum += p[t];
        }
        *(float4*)&pd_out[((size_t)(b * NN + i)) * NN + j0] =
            make_float4(p[0], p[1], p[2], p[3]);
        // wave reduce
        float x = lsum;
        #pragma unroll
        for (int off = 32; off > 0; off >>= 1) x += __shfl_xor(x, off, 64);
        if ((tid & 63) == 0) red[ii][tid >> 6] = x;
    }
    __syncthreads();
    if (tid < IR) {
        pdmean[b * NN + ibase + tid] =
            (red[tid][0] + red[tid][1] + red[tid][2] + red[tid][3]) * (1.0f / 1024.0f);
    }
}

// ---------------- Kernel B: encoder MLP + 3 GVP layers ----------------
// One 64-thread wave per block; GR rows per block.
// Gate computed by ALL 64 lanes via 8x8 partial dots + width-8 shfl reduce
// (was: 8 masked lanes x 90 inst -> now full-wave 12 inst).
#define GR 4
__global__ __launch_bounds__(64) void gvp_kernel(const float* __restrict__ s_in,
                           const float* __restrict__ v_in,
                           const float* __restrict__ enc_w1,
                           const float* __restrict__ enc_b1,
                           const float* __restrict__ enc_w2,
                           const float* __restrict__ enc_b2,
                           const float* __restrict__ scal_w,
                           const float* __restrict__ scal_b,
                           const float* __restrict__ vec_w,
                           const float* __restrict__ gate_w,
                           const float* __restrict__ gate_b,
                           const float* __restrict__ pdmean,
                           float* __restrict__ s_gvp,
                           float* __restrict__ v_out) {
    const int lane = threadIdx.x;          // 0..63
    const int rbase = blockIdx.x * GR;     // grid = 8192/GR

    __shared__ float sc[GR][80];           // [s(64) | vn(8)], padded
    __shared__ float vbuf[GR][24];
    __shared__ float vtb[GR][24];
    __shared__ float gg[GR][8];
    __shared__ float hid[GR][16];

    const int gc = lane >> 3;              // gate output channel 0..7
    const int gi = lane & 7;               // gate input slice

    // preload gate weights for all 3 layers: gw[layer][t] = gate_w[(L*8+gc)*72 + gi + 8t]
    float gw[3][9];
    #pragma unroll
    for (int L = 0; L < 3; ++L) {
        const float* gwr = gate_w + ((size_t)L * 8 + gc) * 72 + gi;
        #pragma unroll
        for (int t = 0; t < 9; ++t) gw[L][t] = gwr[8 * t];
    }

    #pragma unroll
    for (int r = 0; r < GR; ++r) {
        const int row = rbase + r;
        sc[r][lane] = s_in[(size_t)row * 64 + lane];
        if (lane < 24) vbuf[r][lane] = v_in[(size_t)row * 24 + lane];
        if (lane < 16) {
            float pm = pdmean[row];
            hid[r][lane] = silu_f(pm * enc_w1[lane] + enc_b1[lane]);
        }
    }
    __syncthreads();
    #pragma unroll
    for (int r = 0; r < GR; ++r) {
        float acc = enc_b2[lane];
        #pragma unroll
        for (int h = 0; h < 16; ++h) acc += hid[r][h] * enc_w2[lane * 16 + h];
        sc[r][lane] += acc;
    }
    __syncthreads();

    for (int layer = 0; layer < 3; ++layer) {
        const bool act = layer < 2;
        if (lane < 8) {
            #pragma unroll
            for (int r = 0; r < GR; ++r) {
                float x = vbuf[r][lane * 3 + 0];
                float y = vbuf[r][lane * 3 + 1];
                float z = vbuf[r][lane * 3 + 2];
                sc[r][64 + lane] = sqrtf(x * x + y * y + z * z);
            }
        }
        __syncthreads();

        float sn[GR];
        {
            float4 w4[18];
            const float4* wr = (const float4*)(scal_w + ((size_t)layer * 64 + lane) * 72);
            #pragma unroll
            for (int k = 0; k < 18; ++k) w4[k] = wr[k];
            const float sb = scal_b[layer * 64 + lane];
            #pragma unroll
            for (int r = 0; r < GR; ++r) {
                const float4* sv = (const float4*)sc[r];
                float acc = sb;
                #pragma unroll
                for (int k = 0; k < 18; ++k) {
                    float4 s4 = sv[k];
                    acc += w4[k].x * s4.x + w4[k].y * s4.y + w4[k].z * s4.z + w4[k].w * s4.w;
                }
                sn[r] = acc;
            }
        }
        // gate: all 64 lanes; lane (gc,gi) does 9-input partial, reduce over 8 lanes
        {
            const float gb = gate_b[layer * 8 + gc];
            #pragma unroll
            for (int r = 0; r < GR; ++r) {
                float ga = 0.0f;
                #pragma unroll
                for (int t = 0; t < 9; ++t) ga += gw[layer][t] * sc[r][gi + 8 * t];
                ga += __shfl_xor(ga, 1, 8);
                ga += __shfl_xor(ga, 2, 8);
                ga += __shfl_xor(ga, 4, 8);
                if (gi == 0) gg[r][gc] = sigmoid_f(ga + gb);
            }
        }
        if (lane < 24) {
            const int o = lane / 3;
            const int xc = lane - o * 3;
            const float* vw = vec_w + ((size_t)layer * 8 + o) * 8;
            float vwr[8];
            #pragma unroll
            for (int ii = 0; ii < 8; ++ii) vwr[ii] = vw[ii];
            #pragma unroll
            for (int r = 0; r < GR; ++r) {
                float acc = 0.0f;
                #pragma unroll
                for (int ii = 0; ii < 8; ++ii) acc += vwr[ii] * vbuf[r][ii * 3 + xc];
                vtb[r][lane] = acc;
            }
        }
        __syncthreads();

        #pragma unroll
        for (int r = 0; r < GR; ++r) {
            float val = act ? silu_f(sn[r]) : sn[r];
            sc[r][lane] = (layer > 0) ? (sc[r][lane] + val) : val;
        }
        if (lane < 24) {
            const int o = lane / 3;
            #pragma unroll
            for (int r = 0; r < GR; ++r) {
                float val = vtb[r][lane];
                if (act) {
                    float a = vtb[r][o * 3 + 0];
                    float bb2 = vtb[r][o * 3 + 1];
                    float c2 = vtb[r][o * 3 + 2];
                    val *= sigmoid_f(sqrtf(a * a + bb2 * bb2 + c2 * c2));
                }
                val *= gg[r][o];
                vbuf[r][lane] = (layer > 0) ? (vbuf[r][lane] + val) : val;
            }
        }
        __syncthreads();
    }

    #pragma unroll
    for (int r = 0; r < GR; ++r) {
        const int row = rbase + r;
        s_gvp[(size_t)row * 64 + lane] = sc[r][lane];
        if (lane < 24) v_out[(size_t)row * 24 + lane] = vbuf[r][lane];
    }
}

// ---------------- Kernel C: QKV projection (16 rows/block) ----------------
#define QROWS 16
__global__ __launch_bounds__(192) void qkv_kernel(const float* __restrict__ s_gvp,
                           const float* __restrict__ w,
                           const float* __restrict__ bias,
                           float* __restrict__ q,
                           float* __restrict__ k,
                           float* __restrict__ v) {
    const int tid = threadIdx.x;            // 0..191 = output col
    const int rbase = blockIdx.x * QROWS;   // grid 512
    __shared__ float sl[QROWS][64];
    for (int idx = tid; idx < QROWS * 64; idx += 192)
        sl[idx >> 6][idx & 63] = s_gvp[(size_t)rbase * 64 + idx];
    __syncthreads();

    float4 w4[16];
    const float4* wr = (const float4*)(w + (size_t)tid * 64);
    #pragma unroll
    for (int kk = 0; kk < 16; ++kk) w4[kk] = wr[kk];
    const float bv = bias[tid];

    const int which = tid >> 6;
    const int e = tid & 63;
    const int h = e >> 4, d = e & 15;
    float* dst = (which == 0) ? q : (which == 1) ? k : v;

    #pragma unroll
    for (int r = 0; r < QROWS; ++r) {
        const float4* sv = (const float4*)sl[r];
        float acc = bv;
        #pragma unroll
        for (int kk = 0; kk < 16; ++kk) {
            float4 s4 = sv[kk];
            acc += w4[kk].x * s4.x + w4[kk].y * s4.y + w4[kk].z * s4.z + w4[kk].w * s4.w;
        }
        const int row = rbase + r;
        const int b = row >> 10, n = row & 1023;
        dst[(((size_t)(b * HH + h)) * NN + n) * HDD + d] = acc;
    }
}

// ---------------- Kernel D: flash attention, K-split x2, reg-prefetch dbuf ----------------
// Grid: (B*H) * (N/64) * 2 blocks, 256 threads.
// T14 async-stage: next tile's K/V global loads issued into 16 VGPRs right
// after the LDS-ready barrier, consumed by ds_write next iteration -> global
// latency hides under the ~2000-cy compute phase instead of sitting between
// the two barriers.
// __launch_bounds__(256,2) NOT (256,4): forcing 4 waves/SIMD caps VGPR at 64
// and spills (R4: 365MB fetch + 440MB write scratch traffic, 3x slower).
__global__ __launch_bounds__(256, 2)
void attn_kernel(const float* __restrict__ q,
                 const float* __restrict__ k,
                 const float* __restrict__ v,
                 const float* __restrict__ pd,
                 float* __restrict__ po,   // [2][32768][16]
                 float* __restrict__ pm,   // [2][32768]
                 float* __restrict__ pl) { // [2][32768]
    const int ks = blockIdx.x & 1;
    const int qt = (blockIdx.x >> 1) & 15;
    const int bh = blockIdx.x >> 5;        // b*H + h
    const int b = bh >> 2;
    const int tid = threadIdx.x;
    const int kl = tid & 15;
    const int qg = tid >> 4;
    const int qbase = qt * 64 + qg * 4;

    // padded rows (16 -> 20 floats): 2-way bank alias (free)
    __shared__ float kt[128][20];
    __shared__ float vt[128][20];

    float qreg[4][16];
    const float* qb_ = q + ((size_t)bh * NN + qbase) * HDD;
    #pragma unroll
    for (int i = 0; i < 4; ++i) {
        #pragma unroll
        for (int d = 0; d < 16; d += 4) {
            float4 t4 = *(const float4*)(qb_ + i * 16 + d);
            qreg[i][d] = t4.x; qreg[i][d+1] = t4.y; qreg[i][d+2] = t4.z; qreg[i][d+3] = t4.w;
        }
    }
    const float* pdr0 = pd + ((size_t)b * NN + qbase) * NN + ks * 512;

    float acc[4][16];
    #pragma unroll
    for (int i = 0; i < 4; ++i)
        #pragma unroll
        for (int d = 0; d < 16; ++d) acc[i][d] = 0.0f;
    float mrun[4] = {-INFINITY, -INFINITY, -INFINITY, -INFINITY};
    float lrun[4] = {0.0f, 0.0f, 0.0f, 0.0f};

    const float* kbase = k + ((size_t)bh * NN + ks * 512) * HDD;
    const float* vbase = v + ((size_t)bh * NN + ks * 512) * HDD;
    const float kLog2e = 1.44269504f;

    // LDS write slots for this thread (512 float4 per tile, 2 chunks each)
    const int r0 = tid >> 2, s0 = tid & 3;
    const int r1 = (tid + 256) >> 2, s1 = tid & 3;  // (tid+256)&3 == tid&3

    // prologue: prefetch tile 0 into regs
    float4 kp0, kp1, vp0, vp1;
    {
        const float4* kg = (const float4*)kbase;
        const float4* vg = (const float4*)vbase;
        kp0 = kg[tid]; kp1 = kg[tid + 256];
        vp0 = vg[tid]; vp1 = vg[tid + 256];
    }

    for (int tile = 0; tile < 4; ++tile) {
        __syncthreads();   // previous tile's LDS consumers done
        *(float4*)&kt[r0][s0 * 4] = kp0;
        *(float4*)&kt[r1][s1 * 4] = kp1;
        *(float4*)&vt[r0][s0 * 4] = vp0;
        *(float4*)&vt[r1][s1 * 4] = vp1;
        __syncthreads();   // tile ready

        // issue next tile's loads NOW; latency hides under compute below
        if (tile < 3) {
            const float4* kg = (const float4*)(kbase + (size_t)(tile + 1) * 2048);
            const float4* vg = (const float4*)(vbase + (size_t)(tile + 1) * 2048);
            kp0 = kg[tid]; kp1 = kg[tid + 256];
            vp0 = vg[tid]; vp1 = vg[tid + 256];
        }

        float sc[4][8];
        #pragma unroll
        for (int m = 0; m < 8; ++m) {
            const int jt = kl + 16 * m;
            float kr[16];
            #pragma unroll
            for (int d = 0; d < 16; d += 4) {
                float4 t4 = *(const float4*)&kt[jt][d];
                kr[d] = t4.x; kr[d+1] = t4.y; kr[d+2] = t4.z; kr[d+3] = t4.w;
            }
            const int j = tile * 128 + jt;
            #pragma unroll
            for (int i = 0; i < 4; ++i) {
                float a = 0.0f;
                #pragma unroll
                for (int d = 0; d < 16; ++d) a += qreg[i][d] * kr[d];
                sc[i][m] = a * 0.25f - pdr0[(size_t)i * NN + j];
            }
        }

        #pragma unroll
        for (int i = 0; i < 4; ++i) {
            float tmax = sc[i][0];
            #pragma unroll
            for (int m = 1; m < 8; ++m) tmax = fmaxf(tmax, sc[i][m]);
            #pragma unroll
            for (int w = 1; w < 16; w <<= 1) tmax = fmaxf(tmax, __shfl_xor(tmax, w, 16));
            float mnew = fmaxf(mrun[i], tmax);
            float scale = exp2f((mrun[i] - mnew) * kLog2e);
            mrun[i] = mnew;
            lrun[i] *= scale;
            #pragma unroll
            for (int d = 0; d < 16; ++d) acc[i][d] *= scale;
            float ls = 0.0f;
            #pragma unroll
            for (int m = 0; m < 8; ++m) {
                float p = exp2f((sc[i][m] - mnew) * kLog2e);
                sc[i][m] = p;
                ls += p;
            }
            lrun[i] += ls;
        }

        #pragma unroll
        for (int m = 0; m < 8; ++m) {
            const int jt = kl + 16 * m;
            float vr[16];
            #pragma unroll
            for (int d = 0; d < 16; d += 4) {
                float4 t4 = *(const float4*)&vt[jt][d];
                vr[d] = t4.x; vr[d+1] = t4.y; vr[d+2] = t4.z; vr[d+3] = t4.w;
            }
            #pragma unroll
            for (int i = 0; i < 4; ++i) {
                const float p = sc[i][m];
                #pragma unroll
                for (int d = 0; d < 16; ++d) acc[i][d] += p * vr[d];
            }
        }
    }

    // reduce l and acc across the 16 kl lanes; write partials
    #pragma unroll
    for (int i = 0; i < 4; ++i) {
        float l = lrun[i];
        #pragma unroll
        for (int w = 1; w < 16; w <<= 1) l += __shfl_xor(l, w, 16);
        lrun[i] = l;
    }
    float outv[4] = {0.0f, 0.0f, 0.0f, 0.0f};
    #pragma unroll
    for (int i = 0; i < 4; ++i) {
        #pragma unroll
        for (int d = 0; d < 16; ++d) {
            float a = acc[i][d];
            #pragma unroll
            for (int w = 1; w < 16; w <<= 1) a += __shfl_xor(a, w, 16);
            if (kl == d) outv[i] = a;
        }
    }
    const size_t sbase = (size_t)ks * 32768 + (size_t)bh * NN + qbase;
    #pragma unroll
    for (int i = 0; i < 4; ++i) {
        po[(sbase + i) * 16 + kl] = outv[i];
        if (kl == 0) {
            pm[sbase + i] = mrun[i];
            pl[sbase + i] = lrun[i];
        }
    }
}

// ---------------- Kernel E: merge K-split partials + out projection + residual ----------------
#define OROWS 16
__global__ __launch_bounds__(256) void outproj_kernel(const float* __restrict__ s_gvp,
                               const float* __restrict__ po,
                               const float* __restrict__ pm,
                               const float* __restrict__ pl,
                               const float* __restrict__ w,
                               const float* __restrict__ bias,
                               float* __restrict__ s_out) {
    const int tid = threadIdx.x;
    const int col = tid & 63;
    const int wq = tid >> 6;                // wave id 0..3
    const int rbase = blockIdx.x * OROWS;   // grid 512
    __shared__ float ol[OROWS][64];
    const float kLog2e = 1.44269504f;
    for (int idx = tid; idx < OROWS * 64; idx += 256) {
        const int r = idx >> 6;
        const int c = idx & 63;
        const int row = rbase + r;
        const int b = row >> 10, n = row & 1023;
        const int h = c >> 4, d = c & 15;
        const size_t i2 = (size_t)(b * HH + h) * NN + n;
        float m0 = pm[i2], m1 = pm[32768 + i2];
        float l0 = pl[i2], l1 = pl[32768 + i2];
        float a0 = po[i2 * 16 + d], a1 = po[(32768 + i2) * 16 + d];
        float mm = fmaxf(m0, m1);
        float e0 = exp2f((m0 - mm) * kLog2e);
        float e1 = exp2f((m1 - mm) * kLog2e);
        ol[r][c] = (a0 * e0 + a1 * e1) / (l0 * e0 + l1 * e1);
    }
    __syncthreads();

    float4 w4[16];
    const float4* wr = (const float4*)(w + (size_t)col * 64);
    #pragma unroll
    for (int kk = 0; kk < 16; ++kk) w4[kk] = wr[kk];
    const float bv = bias[col];

    #pragma unroll
    for (int rr = 0; rr < OROWS / 4; ++rr) {
        const int r = wq * (OROWS / 4) + rr;
        const float4* sv = (const float4*)ol[r];
        float acc = bv;
        #pragma unroll
        for (int kk = 0; kk < 16; ++kk) {
            float4 s4 = sv[kk];
            acc += w4[kk].x * s4.x + w4[kk].y * s4.y + w4[kk].z * s4.z + w4[kk].w * s4.w;
        }
        const int row = rbase + r;
        s_out[(size_t)row * 64 + col] = s_gvp[(size_t)row * 64 + col] + acc;
    }
}

extern "C" void kernel_launch(void* const* d_in, const int* in_sizes, int n_in,
                              void* d_out, int out_size, void* d_ws, size_t ws_size,
                              hipStream_t stream) {
    const float* s_in      = (const float*)d_in[0];
    const float* v_in      = (const float*)d_in[1];
    const float* coords    = (const float*)d_in[2];
    const float* enc_w1    = (const float*)d_in[3];
    const float* enc_b1    = (const float*)d_in[4];
    const float* enc_w2    = (const float*)d_in[5];
    const float* enc_b2    = (const float*)d_in[6];
    const float* scal_w    = (const float*)d_in[7];
    const float* scal_b    = (const float*)d_in[8];
    const float* vec_w     = (const float*)d_in[9];
    const float* gate_w    = (const float*)d_in[10];
    const float* gate_b    = (const float*)d_in[11];
    const float* in_proj_w = (const float*)d_in[12];
    const float* in_proj_b = (const float*)d_in[13];
    const float* out_proj_w= (const float*)d_in[14];
    const float* out_proj_b= (const float*)d_in[15];

    float* out_s  = (float*)d_out + OUT_S_OFF;
    float* out_v  = (float*)d_out + OUT_V_OFF;
    float* out_pd = (float*)d_out + OUT_PD_OFF;

    // ws layout (floats): pdmean[8192] | s_gvp[524288] | q | k | v [524288 ea]
    //                     | po[2*32768*16] | pm[2*32768] | pl[2*32768]
    float* ws      = (float*)d_ws;
    float* pdmean  = ws;
    float* s_gvp   = ws + 8192;
    float* qb      = s_gvp + 524288;
    float* kb      = qb + 524288;
    float* vvb     = kb + 524288;
    float* po      = vvb + 524288;
    float* pm      = po + 2 * 32768 * 16;
    float* pl      = pm + 2 * 32768;

    const int rows = BB * NN;  // 8192

    pd_kernel<<<BB * (NN / IR), 256, 0, stream>>>(coords, out_pd, pdmean);
    gvp_kernel<<<rows / GR, 64, 0, stream>>>(s_in, v_in, enc_w1, enc_b1, enc_w2, enc_b2,
                                             scal_w, scal_b, vec_w, gate_w, gate_b,
                                             pdmean, s_gvp, out_v);
    qkv_kernel<<<rows / QROWS, 192, 0, stream>>>(s_gvp, in_proj_w, in_proj_b, qb, kb, vvb);
    attn_kernel<<<BB * HH * (NN / 64) * 2, 256, 0, stream>>>(qb, kb, vvb, out_pd, po, pm, pl);
    outproj_kernel<<<rows / OROWS, 256, 0, stream>>>(s_gvp, po, pm, pl,
                                                     out_proj_w, out_proj_b, out_s);
}